// Round 7
// baseline (2693.738 us; speedup 1.0000x reference)
//
#include <hip/hip_runtime.h>
#include <hip/hip_bf16.h>

// Problem: L=D=H=512 self-matching additive attention + bidirectional GRU.
// Inputs f32 (13 tensors), output f32 [512, 1024] = [hf | hb].

#define L 512
#define DD 512
#define HH 512

__device__ __forceinline__ float tanhf_fast(float x) {
    float ex = __expf(2.f * x);
    return 1.f - __fdividef(2.f, ex + 1.f);
}

__device__ __forceinline__ float sigmoidf_fast(float x) {
    return __fdividef(1.f, 1.f + __expf(-x));
}

// ---------------- GEMM body: C[M,N] = A[M,K] * op(B) + bias ----------------
// BT=1: B is [N,K] -> C = A @ B^T ; BT=0: B is [K,N] -> C = A @ B
template <int BT>
__device__ __forceinline__ void gemm_body(
    const float* __restrict__ A, const float* __restrict__ B,
    const float* __restrict__ bias, float* __restrict__ C,
    int M, int N, int K)
{
    __shared__ float As[16][68];
    __shared__ float Bs[16][68];
    int tid = threadIdx.x;
    int m0 = blockIdx.y * 64, n0 = blockIdx.x * 64;
    int tm = (tid & 15) * 4;
    int tn = (tid >> 4) * 4;
    float acc[4][4] = {};

    for (int k0 = 0; k0 < K; k0 += 16) {
        {
            int c = tid & 15, r0 = tid >> 4;
#pragma unroll
            for (int q = 0; q < 4; q++) {
                int r = r0 + q * 16;
                As[c][r] = A[(size_t)(m0 + r) * K + k0 + c];
            }
        }
        if (BT) {
            int c = tid & 15, r0 = tid >> 4;
#pragma unroll
            for (int q = 0; q < 4; q++) {
                int n = r0 + q * 16;
                Bs[c][n] = B[(size_t)(n0 + n) * K + k0 + c];
            }
        } else {
            int n = tid & 63, r0 = tid >> 6;
#pragma unroll
            for (int q = 0; q < 4; q++) {
                int k = r0 + q * 4;
                Bs[k][n] = B[(size_t)(k0 + k) * N + n0 + n];
            }
        }
        __syncthreads();
#pragma unroll
        for (int k = 0; k < 16; k++) {
            float4 av = *(const float4*)&As[k][tm];
            float4 bv = *(const float4*)&Bs[k][tn];
            float a[4] = {av.x, av.y, av.z, av.w};
            float b[4] = {bv.x, bv.y, bv.z, bv.w};
#pragma unroll
            for (int i = 0; i < 4; i++)
#pragma unroll
                for (int j = 0; j < 4; j++) acc[i][j] += a[i] * b[j];
        }
        __syncthreads();
    }
#pragma unroll
    for (int i = 0; i < 4; i++) {
        float4 o;
        o.x = acc[i][0] + (bias ? bias[n0 + tn + 0] : 0.f);
        o.y = acc[i][1] + (bias ? bias[n0 + tn + 1] : 0.f);
        o.z = acc[i][2] + (bias ? bias[n0 + tn + 2] : 0.f);
        o.w = acc[i][3] + (bias ? bias[n0 + tn + 3] : 0.f);
        *(float4*)&C[(size_t)(m0 + tm + i) * N + n0 + tn] = o;
    }
}

template <int BT>
__global__ __launch_bounds__(256) void gemm_k(
    const float* __restrict__ A, const float* __restrict__ B,
    const float* __restrict__ bias, float* __restrict__ C,
    int M, int N, int K)
{
    gemm_body<BT>(A, B, bias, C, M, N, K);
}

// two independent GEMMs sharing A, selected by blockIdx.z
template <int BT>
__global__ __launch_bounds__(256) void gemm2_k(
    const float* __restrict__ A,
    const float* __restrict__ B0, const float* __restrict__ B1,
    const float* __restrict__ bias0, const float* __restrict__ bias1,
    float* __restrict__ C0, float* __restrict__ C1,
    int M, int N, int K)
{
    if (blockIdx.z == 0) gemm_body<BT>(A, B0, bias0, C0, M, N, K);
    else                 gemm_body<BT>(A, B1, bias1, C1, M, N, K);
}

// ---------------- attention scores e[t,j] = sum_d tanh(u[j,d]+w[t,d]) * v[j,d] ----
__global__ __launch_bounds__(256) void attn_e_k(
    const float* __restrict__ u, const float* __restrict__ w,
    const float* __restrict__ v, float* __restrict__ e)
{
    __shared__ float wS[16][68];
    __shared__ float uS[32][68];
    __shared__ float vS[32][68];
    int tid = threadIdx.x;
    int t0 = blockIdx.y * 16, j0 = blockIdx.x * 32;
    int tt = tid >> 5, jj = tid & 31;
    float acc0 = 0.f, acc1 = 0.f;

    for (int d0 = 0; d0 < DD; d0 += 64) {
        {
            int c = tid & 63, r0 = tid >> 6;
#pragma unroll
            for (int q = 0; q < 4; q++)
                wS[r0 + q * 4][c] = w[(size_t)(t0 + r0 + q * 4) * DD + d0 + c];
#pragma unroll
            for (int q = 0; q < 8; q++) {
                int r = r0 + q * 4;
                uS[r][c] = u[(size_t)(j0 + r) * DD + d0 + c];
                vS[r][c] = v[(size_t)(j0 + r) * DD + d0 + c];
            }
        }
        __syncthreads();
#pragma unroll
        for (int c4 = 0; c4 < 16; c4++) {
            float4 uv = *(const float4*)&uS[jj][c4 * 4];
            float4 vv = *(const float4*)&vS[jj][c4 * 4];
            float4 w0 = *(const float4*)&wS[tt][c4 * 4];
            float4 w1 = *(const float4*)&wS[tt + 8][c4 * 4];
            acc0 += tanhf_fast(uv.x + w0.x) * vv.x;
            acc0 += tanhf_fast(uv.y + w0.y) * vv.y;
            acc0 += tanhf_fast(uv.z + w0.z) * vv.z;
            acc0 += tanhf_fast(uv.w + w0.w) * vv.w;
            acc1 += tanhf_fast(uv.x + w1.x) * vv.x;
            acc1 += tanhf_fast(uv.y + w1.y) * vv.y;
            acc1 += tanhf_fast(uv.z + w1.z) * vv.z;
            acc1 += tanhf_fast(uv.w + w1.w) * vv.w;
        }
        __syncthreads();
    }
    e[(size_t)(t0 + tt) * L + j0 + jj] = acc0;
    e[(size_t)(t0 + tt + 8) * L + j0 + jj] = acc1;
}

// ---------------- row softmax (in place) ----------------
__global__ __launch_bounds__(256) void softmax_k(float* __restrict__ e) {
    int t = blockIdx.x;
    float* row = e + (size_t)t * L;
    int tid = threadIdx.x;
    float v0 = row[tid], v1 = row[tid + 256];
    float m = fmaxf(v0, v1);
#pragma unroll
    for (int off = 32; off > 0; off >>= 1) m = fmaxf(m, __shfl_xor(m, off));
    __shared__ float red[4];
    __shared__ float red2[4];
    int wid = tid >> 6, lane = tid & 63;
    if (lane == 0) red[wid] = m;
    __syncthreads();
    m = fmaxf(fmaxf(red[0], red[1]), fmaxf(red[2], red[3]));
    float e0 = __expf(v0 - m), e1 = __expf(v1 - m);
    float s = e0 + e1;
#pragma unroll
    for (int off = 32; off > 0; off >>= 1) s += __shfl_xor(s, off);
    if (lane == 0) red2[wid] = s;
    __syncthreads();
    s = red2[0] + red2[1] + red2[2] + red2[3];
    float inv = __fdividef(1.f, s);
    row[tid] = e0 * inv;
    row[tid + 256] = e1 * inv;
}

// ---------------- x = [v, c] ----------------
__global__ __launch_bounds__(256) void concat_k(
    const float* __restrict__ v, const float* __restrict__ c, float* __restrict__ x)
{
    int idx = blockIdx.x * 256 + threadIdx.x;
    int t = idx >> 10, j = idx & 1023;
    x[idx] = (j < DD) ? v[(size_t)t * DD + j] : c[(size_t)t * DD + (j - DD)];
}

// ---------------- GRU scan: wave-autonomous units ----------------
// 128 blocks x 128 threads = 256 waves. Each WAVE is an independent unit
// owning 4 h-indices (12 whh rows in registers; lane owns h-columns
// [8*lane, 8*lane+8)). h lives in REGISTERS: each lane polls its own 8
// encoded words straight from L3 (merged data+tag u32, 24-bit fixed point
// scale 2^22 + 8-bit step tag), decodes in-register. gh via 12-value
// butterfly shfl reduce. Lanes 0..3 compute gates (h_prev kept lane-local,
// full precision) and store 4 tagged words + full-precision out row.
// ZERO __syncthreads, ZERO LDS. Parity ping-pong; skew <= 1 step => tags
// (mod 256, stride 2 per parity) never alias; 0xAA poison can't match
// tags 1/2 of the first polls => no memset needed.
__global__ __launch_bounds__(128) void gru_scan_k(
    const float* __restrict__ whh_f, const float* __restrict__ bhh_f,
    const float* __restrict__ whh_b, const float* __restrict__ bhh_b,
    const float* __restrict__ gi_f, const float* __restrict__ gi_b,
    float* __restrict__ out,
    unsigned* __restrict__ hstage)   // [2 dirs][2 parity][512] encoded u32
{
    int blk = blockIdx.x;
    int dir = blk >> 6;                      // 0 fwd, 1 bwd
    int wv  = threadIdx.x >> 6;              // wave within block
    int lane = threadIdx.x & 63;
    int ul = ((blk & 63) << 1) | wv;         // unit 0..127 within direction
    int hbase = ul * 4;

    const float* whh = dir ? whh_b : whh_f;
    const float* bhh = dir ? bhh_b : bhh_f;
    const float* gi  = dir ? gi_b : gi_f;
    float* outBase = out + dir * HH;         // row stride 1024
    unsigned* stage = hstage + dir * 1024;

    // 12 rows (g*4+i) of whh, this lane's 8 columns
    float4 wa[12], wb[12];
#pragma unroll
    for (int g = 0; g < 3; g++)
#pragma unroll
        for (int i = 0; i < 4; i++) {
            const float* row = whh + (size_t)(g * HH + hbase + i) * HH + lane * 8;
            wa[g * 4 + i] = *(const float4*)row;
            wb[g * 4 + i] = *(const float4*)(row + 4);
        }

    float bhr = 0.f, bhz = 0.f, bhn = 0.f, hp = 0.f;
    if (lane < 4) {
        bhr = bhh[0 * HH + hbase + lane];
        bhz = bhh[1 * HH + hbase + lane];
        bhn = bhh[2 * HH + hbase + lane];
    }

    float h[8];
#pragma unroll
    for (int j = 0; j < 8; j++) h[j] = 0.f;

    float ir = 0.f, iz = 0.f, inn = 0.f;
    if (lane < 4) {
        int t0 = dir ? (L - 1) : 0;
        const float* git = gi + (size_t)t0 * (3 * HH);
        ir  = git[hbase + lane];
        iz  = git[HH + hbase + lane];
        inn = git[2 * HH + hbase + lane];
    }

    const float ENC = 4194304.0f;            // 2^22
    const float DEC = 1.0f / 4194304.0f;

    for (int s = 0; s < L; s++) {
        int t = dir ? (L - 1 - s) : s;

        // matvec partials: 12 rows x this lane's 8 h columns
        float acc[12];
#pragma unroll
        for (int r = 0; r < 12; r++) {
            acc[r] = wa[r].x * h[0] + wa[r].y * h[1] + wa[r].z * h[2] + wa[r].w * h[3]
                   + wb[r].x * h[4] + wb[r].y * h[5] + wb[r].z * h[6] + wb[r].w * h[7];
        }
        // butterfly reduce all 12 across the wave
#pragma unroll
        for (int off = 32; off > 0; off >>= 1) {
#pragma unroll
            for (int r = 0; r < 12; r++) acc[r] += __shfl_xor(acc[r], off);
        }

        if (lane < 4) {
            float r = sigmoidf_fast(ir + acc[lane] + bhr);
            float z = sigmoidf_fast(iz + acc[4 + lane] + bhz);
            float n = tanhf_fast(inn + r * (acc[8 + lane] + bhn));
            float hnew = (1.f - z) * n + z * hp;
            hp = hnew;
            outBase[(size_t)t * 1024 + hbase + lane] = hnew;
            unsigned enc = ((unsigned)__float2int_rn(hnew * ENC) & 0x00FFFFFFu)
                         | ((unsigned)((s + 1) & 0xFF) << 24);
            __hip_atomic_store(stage + (s & 1) * 512 + hbase + lane, enc,
                               __ATOMIC_RELAXED, __HIP_MEMORY_SCOPE_AGENT);
        }

        if (s == L - 1) break;

        // prefetch next step's gi while waiting
        if (lane < 4) {
            int tn = dir ? (L - 2 - s) : (s + 1);
            const float* git = gi + (size_t)tn * (3 * HH);
            ir  = git[hbase + lane];
            iz  = git[HH + hbase + lane];
            inn = git[2 * HH + hbase + lane];
        }

        // poll this lane's 8 words (data IS the flag), decode into regs
        {
            unsigned tag = (unsigned)((s + 1) & 0xFF);
            const unsigned* src = stage + (s & 1) * 512 + lane * 8;
            unsigned ew[8];
            bool ok;
            do {
                ok = true;
#pragma unroll
                for (int j = 0; j < 8; j++) {
                    ew[j] = __hip_atomic_load(src + j, __ATOMIC_RELAXED,
                                              __HIP_MEMORY_SCOPE_AGENT);
                    ok &= ((ew[j] >> 24) == tag);
                }
            } while (!__all(ok));
#pragma unroll
            for (int j = 0; j < 8; j++)
                h[j] = (float)(((int)(ew[j] << 8)) >> 8) * DEC;
        }
    }
}

extern "C" void kernel_launch(void* const* d_in, const int* in_sizes, int n_in,
                              void* d_out, int out_size, void* d_ws, size_t ws_size,
                              hipStream_t stream) {
    const float* v     = (const float*)d_in[0];
    const float* w1    = (const float*)d_in[1];
    const float* b1    = (const float*)d_in[2];
    const float* w2    = (const float*)d_in[3];
    const float* b2    = (const float*)d_in[4];
    const float* wih_f = (const float*)d_in[5];
    const float* whh_f = (const float*)d_in[6];
    const float* bih_f = (const float*)d_in[7];
    const float* bhh_f = (const float*)d_in[8];
    const float* wih_b = (const float*)d_in[9];
    const float* whh_b = (const float*)d_in[10];
    const float* bih_b = (const float*)d_in[11];
    const float* bhh_b = (const float*)d_in[12];
    float* out = (float*)d_out;   // f32 [512, 1024]

    float* ws = (float*)d_ws;
    float* u   = ws;                 // 512*512
    float* w_  = ws + 262144;        // 512*512
    float* e   = ws + 524288;        // 512*512 (becomes a after softmax)
    float* c   = ws + 786432;        // 512*512
    float* x   = ws + 1048576;       // 512*1024
    float* gif = ws + 1572864;       // 512*1536
    float* gib = ws + 2359296;       // 512*1536
    unsigned* hstage = (unsigned*)(ws + 3145728);  // 2*2*512 u32 (no init needed)

    // u = v @ w1^T + b1 ; w = v @ w2^T + b2  (one launch, z selects)
    gemm2_k<1><<<dim3(8, 8, 2), 256, 0, stream>>>(v, w1, w2, b1, b2, u, w_,
                                                  512, 512, 512);

    // e[t,j] = sum_d tanh(u[j,d]+w[t,d]) v[j,d]
    attn_e_k<<<dim3(16, 32), 256, 0, stream>>>(u, w_, v, e);
    softmax_k<<<512, 256, 0, stream>>>(e);

    // c = a @ v
    gemm_k<0><<<dim3(8, 8), 256, 0, stream>>>(e, v, nullptr, c, 512, 512, 512);

    // x = [v, c]
    concat_k<<<2048, 256, 0, stream>>>(v, c, x);

    // gi = x @ wih^T + bih, both directions in one launch
    gemm2_k<1><<<dim3(24, 8, 2), 256, 0, stream>>>(x, wih_f, wih_b, bih_f, bih_b,
                                                   gif, gib, 512, 1536, 1024);

    gru_scan_k<<<128, 128, 0, stream>>>(whh_f, bhh_f, whh_b, bhh_b,
                                        gif, gib, out, hstage);
}

// Round 8
// 1327.738 us; speedup vs baseline: 2.0288x; 2.0288x over previous
//
#include <hip/hip_runtime.h>
#include <hip/hip_bf16.h>

// Problem: L=D=H=512 self-matching additive attention + bidirectional GRU.
// Inputs f32 (13 tensors), output f32 [512, 1024] = [hf | hb].

#define L 512
#define DD 512
#define HH 512

__device__ __forceinline__ float tanhf_fast(float x) {
    float ex = __expf(2.f * x);
    return 1.f - __fdividef(2.f, ex + 1.f);
}

__device__ __forceinline__ float sigmoidf_fast(float x) {
    return __fdividef(1.f, 1.f + __expf(-x));
}

// ---------------- GEMM body: C[M,N] = A[M,K] * op(B) + bias ----------------
// BT=1: B is [N,K] -> C = A @ B^T ; BT=0: B is [K,N] -> C = A @ B
template <int BT>
__device__ __forceinline__ void gemm_body(
    const float* __restrict__ A, const float* __restrict__ B,
    const float* __restrict__ bias, float* __restrict__ C,
    int M, int N, int K)
{
    __shared__ float As[16][68];
    __shared__ float Bs[16][68];
    int tid = threadIdx.x;
    int m0 = blockIdx.y * 64, n0 = blockIdx.x * 64;
    int tm = (tid & 15) * 4;
    int tn = (tid >> 4) * 4;
    float acc[4][4] = {};

    for (int k0 = 0; k0 < K; k0 += 16) {
        {
            int c = tid & 15, r0 = tid >> 4;
#pragma unroll
            for (int q = 0; q < 4; q++) {
                int r = r0 + q * 16;
                As[c][r] = A[(size_t)(m0 + r) * K + k0 + c];
            }
        }
        if (BT) {
            int c = tid & 15, r0 = tid >> 4;
#pragma unroll
            for (int q = 0; q < 4; q++) {
                int n = r0 + q * 16;
                Bs[c][n] = B[(size_t)(n0 + n) * K + k0 + c];
            }
        } else {
            int n = tid & 63, r0 = tid >> 6;
#pragma unroll
            for (int q = 0; q < 4; q++) {
                int k = r0 + q * 4;
                Bs[k][n] = B[(size_t)(k0 + k) * N + n0 + n];
            }
        }
        __syncthreads();
#pragma unroll
        for (int k = 0; k < 16; k++) {
            float4 av = *(const float4*)&As[k][tm];
            float4 bv = *(const float4*)&Bs[k][tn];
            float a[4] = {av.x, av.y, av.z, av.w};
            float b[4] = {bv.x, bv.y, bv.z, bv.w};
#pragma unroll
            for (int i = 0; i < 4; i++)
#pragma unroll
                for (int j = 0; j < 4; j++) acc[i][j] += a[i] * b[j];
        }
        __syncthreads();
    }
#pragma unroll
    for (int i = 0; i < 4; i++) {
        float4 o;
        o.x = acc[i][0] + (bias ? bias[n0 + tn + 0] : 0.f);
        o.y = acc[i][1] + (bias ? bias[n0 + tn + 1] : 0.f);
        o.z = acc[i][2] + (bias ? bias[n0 + tn + 2] : 0.f);
        o.w = acc[i][3] + (bias ? bias[n0 + tn + 3] : 0.f);
        *(float4*)&C[(size_t)(m0 + tm + i) * N + n0 + tn] = o;
    }
}

template <int BT>
__global__ __launch_bounds__(256) void gemm_k(
    const float* __restrict__ A, const float* __restrict__ B,
    const float* __restrict__ bias, float* __restrict__ C,
    int M, int N, int K)
{
    gemm_body<BT>(A, B, bias, C, M, N, K);
}

// two independent GEMMs sharing A, selected by blockIdx.z
template <int BT>
__global__ __launch_bounds__(256) void gemm2_k(
    const float* __restrict__ A,
    const float* __restrict__ B0, const float* __restrict__ B1,
    const float* __restrict__ bias0, const float* __restrict__ bias1,
    float* __restrict__ C0, float* __restrict__ C1,
    int M, int N, int K)
{
    if (blockIdx.z == 0) gemm_body<BT>(A, B0, bias0, C0, M, N, K);
    else                 gemm_body<BT>(A, B1, bias1, C1, M, N, K);
}

// gi GEMM with fused concat: A = [v | c] (virtual [512,1024]), B^T layout.
// M=512, N=1536, K=1024; K-tiles (16-wide) never straddle the 512 boundary.
__global__ __launch_bounds__(256) void gemm_gi_k(
    const float* __restrict__ v, const float* __restrict__ cc_,
    const float* __restrict__ B0, const float* __restrict__ B1,
    const float* __restrict__ bias0, const float* __restrict__ bias1,
    float* __restrict__ C0, float* __restrict__ C1)
{
    const float* B    = blockIdx.z ? B1 : B0;
    const float* bias = blockIdx.z ? bias1 : bias0;
    float* C          = blockIdx.z ? C1 : C0;
    const int N = 1536, K = 1024;

    __shared__ float As[16][68];
    __shared__ float Bs[16][68];
    int tid = threadIdx.x;
    int m0 = blockIdx.y * 64, n0 = blockIdx.x * 64;
    int tm = (tid & 15) * 4;
    int tn = (tid >> 4) * 4;
    float acc[4][4] = {};

    for (int k0 = 0; k0 < K; k0 += 16) {
        const float* Asrc = (k0 < 512) ? v : cc_;
        int koff = (k0 < 512) ? k0 : (k0 - 512);
        {
            int c = tid & 15, r0 = tid >> 4;
#pragma unroll
            for (int q = 0; q < 4; q++) {
                int r = r0 + q * 16;
                As[c][r] = Asrc[(size_t)(m0 + r) * 512 + koff + c];
            }
        }
        {
            int c = tid & 15, r0 = tid >> 4;
#pragma unroll
            for (int q = 0; q < 4; q++) {
                int n = r0 + q * 16;
                Bs[c][n] = B[(size_t)(n0 + n) * K + k0 + c];
            }
        }
        __syncthreads();
#pragma unroll
        for (int k = 0; k < 16; k++) {
            float4 av = *(const float4*)&As[k][tm];
            float4 bv = *(const float4*)&Bs[k][tn];
            float a[4] = {av.x, av.y, av.z, av.w};
            float b[4] = {bv.x, bv.y, bv.z, bv.w};
#pragma unroll
            for (int i = 0; i < 4; i++)
#pragma unroll
                for (int j = 0; j < 4; j++) acc[i][j] += a[i] * b[j];
        }
        __syncthreads();
    }
#pragma unroll
    for (int i = 0; i < 4; i++) {
        float4 o;
        o.x = acc[i][0] + bias[n0 + tn + 0];
        o.y = acc[i][1] + bias[n0 + tn + 1];
        o.z = acc[i][2] + bias[n0 + tn + 2];
        o.w = acc[i][3] + bias[n0 + tn + 3];
        *(float4*)&C[(size_t)(m0 + tm + i) * N + n0 + tn] = o;
    }
}

// ---------------- attention scores e[t,j] = sum_d tanh(u[j,d]+w[t,d]) * v[j,d] ----
__global__ __launch_bounds__(256) void attn_e_k(
    const float* __restrict__ u, const float* __restrict__ w,
    const float* __restrict__ v, float* __restrict__ e)
{
    __shared__ float wS[16][68];
    __shared__ float uS[32][68];
    __shared__ float vS[32][68];
    int tid = threadIdx.x;
    int t0 = blockIdx.y * 16, j0 = blockIdx.x * 32;
    int tt = tid >> 5, jj = tid & 31;
    float acc0 = 0.f, acc1 = 0.f;

    for (int d0 = 0; d0 < DD; d0 += 64) {
        {
            int c = tid & 63, r0 = tid >> 6;
#pragma unroll
            for (int q = 0; q < 4; q++)
                wS[r0 + q * 4][c] = w[(size_t)(t0 + r0 + q * 4) * DD + d0 + c];
#pragma unroll
            for (int q = 0; q < 8; q++) {
                int r = r0 + q * 4;
                uS[r][c] = u[(size_t)(j0 + r) * DD + d0 + c];
                vS[r][c] = v[(size_t)(j0 + r) * DD + d0 + c];
            }
        }
        __syncthreads();
#pragma unroll
        for (int c4 = 0; c4 < 16; c4++) {
            float4 uv = *(const float4*)&uS[jj][c4 * 4];
            float4 vv = *(const float4*)&vS[jj][c4 * 4];
            float4 w0 = *(const float4*)&wS[tt][c4 * 4];
            float4 w1 = *(const float4*)&wS[tt + 8][c4 * 4];
            acc0 += tanhf_fast(uv.x + w0.x) * vv.x;
            acc0 += tanhf_fast(uv.y + w0.y) * vv.y;
            acc0 += tanhf_fast(uv.z + w0.z) * vv.z;
            acc0 += tanhf_fast(uv.w + w0.w) * vv.w;
            acc1 += tanhf_fast(uv.x + w1.x) * vv.x;
            acc1 += tanhf_fast(uv.y + w1.y) * vv.y;
            acc1 += tanhf_fast(uv.z + w1.z) * vv.z;
            acc1 += tanhf_fast(uv.w + w1.w) * vv.w;
        }
        __syncthreads();
    }
    e[(size_t)(t0 + tt) * L + j0 + jj] = acc0;
    e[(size_t)(t0 + tt + 8) * L + j0 + jj] = acc1;
}

// ---------------- row softmax (in place) ----------------
__global__ __launch_bounds__(256) void softmax_k(float* __restrict__ e) {
    int t = blockIdx.x;
    float* row = e + (size_t)t * L;
    int tid = threadIdx.x;
    float v0 = row[tid], v1 = row[tid + 256];
    float m = fmaxf(v0, v1);
#pragma unroll
    for (int off = 32; off > 0; off >>= 1) m = fmaxf(m, __shfl_xor(m, off));
    __shared__ float red[4];
    __shared__ float red2[4];
    int wid = tid >> 6, lane = tid & 63;
    if (lane == 0) red[wid] = m;
    __syncthreads();
    m = fmaxf(fmaxf(red[0], red[1]), fmaxf(red[2], red[3]));
    float e0 = __expf(v0 - m), e1 = __expf(v1 - m);
    float s = e0 + e1;
#pragma unroll
    for (int off = 32; off > 0; off >>= 1) s += __shfl_xor(s, off);
    if (lane == 0) red2[wid] = s;
    __syncthreads();
    s = red2[0] + red2[1] + red2[2] + red2[3];
    float inv = __fdividef(1.f, s);
    row[tid] = e0 * inv;
    row[tid + 256] = e1 * inv;
}

// ---------------- GRU scan (round-6 topology + fused u64 pair polls) ------
// 128 blocks x 256 threads. blocks [0,64): forward, [64,128): backward.
// Each block owns 8 h-indices (24 whh rows in registers, interleaved column
// layout => bank-conflict-free LDS matvec). h exchange via SELF-VALIDATING
// words (24-bit fixed point scale 2^22 + 8-bit step tag per u32); consumer
// thread t polls words {2t,2t+1} with ONE 8-byte relaxed atomic load (each
// word self-validates; pair atomicity not required). Ping-pong parity
// buffers; skew <= 1 step => tags never alias; 0xAA poison can't match
// tags 1/2 of the first polls => no memset needed.
__global__ __launch_bounds__(256) void gru_scan_k(
    const float* __restrict__ whh_f, const float* __restrict__ bhh_f,
    const float* __restrict__ whh_b, const float* __restrict__ bhh_b,
    const float* __restrict__ gi_f, const float* __restrict__ gi_b,
    float* __restrict__ out,
    unsigned* __restrict__ hstage)   // [2 dirs][2 parity][512] encoded u32
{
    int blk = blockIdx.x;
    int dir = blk >> 6;          // 0 fwd, 1 bwd
    int bi = blk & 63;
    int hbase = bi * 8;
    const float* whh = dir ? whh_b : whh_f;
    const float* bhh = dir ? bhh_b : bhh_f;
    const float* gi  = dir ? gi_b : gi_f;
    float* outBase = out + dir * HH;       // row stride 1024
    unsigned* stage = hstage + dir * 1024;

    __shared__ float hS[HH];
    __shared__ float ghS[24];

    int tid = threadIdx.x;
    int rr = tid >> 3, c8 = tid & 7;
    bool active = rr < 24;

    // whh weights into registers, interleaved columns: thread c8 owns float4
    // slots {q*8 + c8 : q in [0,16)} of its row (conflict-free LDS reads).
    float4 wreg[16];
    float bhv = 0.f;
    if (active) {
        int g = rr >> 3, i = rr & 7;
        const float4* wrow = (const float4*)(whh + (size_t)(g * HH + hbase + i) * HH);
#pragma unroll
        for (int q = 0; q < 16; q++) wreg[q] = wrow[q * 8 + c8];
        if (c8 == 0) bhv = bhh[g * HH + hbase + i];
    }
    for (int j = tid; j < HH; j += 256) hS[j] = 0.f;

    // prefetch gi for step 0
    float ir = 0.f, iz = 0.f, inn = 0.f;
    if (tid < 8) {
        int t0 = dir ? (L - 1) : 0;
        const float* git = gi + (size_t)t0 * (3 * HH);
        ir  = git[hbase + tid];
        iz  = git[HH + hbase + tid];
        inn = git[2 * HH + hbase + tid];
    }
    __syncthreads();

    const float ENC = 4194304.0f;            // 2^22
    const float DEC = 1.0f / 4194304.0f;

    for (int s = 0; s < L; s++) {
        int t = dir ? (L - 1 - s) : s;

        float acc = 0.f;
        if (active) {
            const float4* h4 = (const float4*)hS;
#pragma unroll
            for (int q = 0; q < 16; q++) {
                float4 hv = h4[q * 8 + c8];   // lanes 16B apart: all 32 banks
                acc += wreg[q].x * hv.x + wreg[q].y * hv.y
                     + wreg[q].z * hv.z + wreg[q].w * hv.w;
            }
            acc += __shfl_xor(acc, 1);
            acc += __shfl_xor(acc, 2);
            acc += __shfl_xor(acc, 4);
            if (c8 == 0) ghS[rr] = acc + bhv;
        }
        __syncthreads();

        if (tid < 8) {
            int i = tid, hg = hbase + i;
            float r = sigmoidf_fast(ir + ghS[i]);
            float z = sigmoidf_fast(iz + ghS[8 + i]);
            float n = tanhf_fast(inn + r * ghS[16 + i]);
            float hnew = (1.f - z) * n + z * hS[hg];
            // tagged store FIRST (latency-critical), out store second
            unsigned enc = ((unsigned)__float2int_rn(hnew * ENC) & 0x00FFFFFFu)
                         | ((unsigned)((s + 1) & 0xFF) << 24);
            __hip_atomic_store(stage + (s & 1) * 512 + hg, enc,
                               __ATOMIC_RELAXED, __HIP_MEMORY_SCOPE_AGENT);
            outBase[(size_t)t * 1024 + hg] = hnew;
        }

        if (s == L - 1) break;

        // prefetch next step's gi while waiting on data
        if (tid < 8) {
            int tn = dir ? (L - 2 - s) : (s + 1);
            const float* git = gi + (size_t)tn * (3 * HH);
            ir  = git[hbase + tid];
            iz  = git[HH + hbase + tid];
            inn = git[2 * HH + hbase + tid];
        }

        // poll this thread's adjacent word pair with one 8B load
        {
            unsigned tag = (unsigned)((s + 1) & 0xFF);
            const unsigned long long* src =
                (const unsigned long long*)(stage + (s & 1) * 512) + tid;
            unsigned long long pair;
            unsigned e0, e1;
            do {
                pair = __hip_atomic_load(src, __ATOMIC_RELAXED,
                                         __HIP_MEMORY_SCOPE_AGENT);
                e0 = (unsigned)pair;
                e1 = (unsigned)(pair >> 32);
            } while (((e0 >> 24) != tag) || ((e1 >> 24) != tag));
            float2 hv;
            hv.x = (float)(((int)(e0 << 8)) >> 8) * DEC;
            hv.y = (float)(((int)(e1 << 8)) >> 8) * DEC;
            *(float2*)&hS[2 * tid] = hv;
        }
        __syncthreads();
    }
}

extern "C" void kernel_launch(void* const* d_in, const int* in_sizes, int n_in,
                              void* d_out, int out_size, void* d_ws, size_t ws_size,
                              hipStream_t stream) {
    const float* v     = (const float*)d_in[0];
    const float* w1    = (const float*)d_in[1];
    const float* b1    = (const float*)d_in[2];
    const float* w2    = (const float*)d_in[3];
    const float* b2    = (const float*)d_in[4];
    const float* wih_f = (const float*)d_in[5];
    const float* whh_f = (const float*)d_in[6];
    const float* bih_f = (const float*)d_in[7];
    const float* bhh_f = (const float*)d_in[8];
    const float* wih_b = (const float*)d_in[9];
    const float* whh_b = (const float*)d_in[10];
    const float* bih_b = (const float*)d_in[11];
    const float* bhh_b = (const float*)d_in[12];
    float* out = (float*)d_out;   // f32 [512, 1024]

    float* ws = (float*)d_ws;
    float* u   = ws;                 // 512*512
    float* w_  = ws + 262144;        // 512*512
    float* e   = ws + 524288;        // 512*512 (becomes a after softmax)
    float* c   = ws + 786432;        // 512*512
    float* gif = ws + 1572864;       // 512*1536
    float* gib = ws + 2359296;       // 512*1536
    unsigned* hstage = (unsigned*)(ws + 3145728);  // 2*2*512 u32 (no init needed)

    // u = v @ w1^T + b1 ; w = v @ w2^T + b2  (one launch, z selects)
    gemm2_k<1><<<dim3(8, 8, 2), 256, 0, stream>>>(v, w1, w2, b1, b2, u, w_,
                                                  512, 512, 512);

    // e[t,j] = sum_d tanh(u[j,d]+w[t,d]) v[j,d]
    attn_e_k<<<dim3(16, 32), 256, 0, stream>>>(u, w_, v, e);
    softmax_k<<<512, 256, 0, stream>>>(e);

    // c = a @ v
    gemm_k<0><<<dim3(8, 8), 256, 0, stream>>>(e, v, nullptr, c, 512, 512, 512);

    // gi = [v|c] @ wih^T + bih, both directions, concat fused into A-load
    gemm_gi_k<<<dim3(24, 8, 2), 256, 0, stream>>>(v, c, wih_f, wih_b,
                                                  bih_f, bih_b, gif, gib);

    gru_scan_k<<<128, 256, 0, stream>>>(whh_f, bhh_f, whh_b, bhh_b,
                                        gif, gib, out, hstage);
}